// Round 8
// baseline (495.327 us; speedup 1.0000x reference)
//
#include <hip/hip_runtime.h>

// LSTM T=512, B=4096, I=10, H=20, fp32.
// Lane = (batch, unit, gate); block = 320 = 4 batch x 20 units x 4 gates.
// Round-8 vs round-7 (333us, VGPR=32: RA spilled the asm-pinned weights to
// scratch; ~123 VALU instr/lane/step vs ~50 needed):
//  1. launch_bounds(320,4): VGPR cap 96->128 so the ~90-reg pressure peak fits
//     and the weights are not eviction victims. No asm pinning (it forced
//     scratch; remat is the worst case without it).
//  2. Vector LDS reads: x row = float4 x2 + float2, h row = float4 x5
//     (30 -> 8 DS ops/lane/step; fewer hoisted live values, less DS-pipe load).
//  3. Two FMA accumulators to halve the dependent-chain latency.
// Kept from round 7: DPP quad_perm gate broadcast (bank conflicts 0),
// x-prefetch spread over lanes 0..7 of each wave.

constexpr int kT = 512, kB = 4096, kI = 10, kH = 20;
constexpr int BPB = 4;                  // batch elements per block
constexpr int THREADS = BPB * kH * 4;   // 320 = 5 waves

__global__ __launch_bounds__(THREADS, 4) void lstm_v5(
    const float* __restrict__ x, const float* __restrict__ hx,
    const float* __restrict__ cx, const float* __restrict__ W_ih,
    const float* __restrict__ W_hh, const float* __restrict__ b_ih,
    const float* __restrict__ b_hh, float* __restrict__ out)
{
    __shared__ float h_s[2][BPB][kH];    // rows 80 B (16B-aligned)
    __shared__ float x_s[2][BPB][12];    // rows padded to 48 B (16B-aligned)

    const int tid = threadIdx.x;
    const int b_loc = tid / 80;          // 0..3
    const int r = tid % 80;
    const int u = r >> 2;                // 0..19
    const int k = r & 3;                 // 0:i 1:f 2:g 3:o (PyTorch order)
    const int b0 = blockIdx.x * BPB;
    const int b = b0 + b_loc;
    const int row = k * kH + u;

    // ---- per-lane weights (statically indexed; cap=128 keeps them resident) ----
    float Wih[kI], Whh[kH];
    #pragma unroll
    for (int i = 0; i < kI; ++i) Wih[i] = W_ih[row * kI + i];
    #pragma unroll
    for (int j = 0; j < kH; ++j) Whh[j] = W_hh[row * kH + j];
    const float bias = b_ih[row] + b_hh[row];

    // unified activation: act = fma(rcp(1+exp2(c0*a)), c1, c2)
    // sigmoid: c0=-log2(e), c1=1, c2=0 ; tanh: c0=-2log2(e), c1=2, c2=-1
    const float c0 = (k == 2) ? -2.885390082f : -1.442695041f;
    const float c1 = (k == 2) ? 2.0f : 1.0f;
    const float c2 = (k == 2) ? -1.0f : 0.0f;

    float c = cx[(size_t)b * kH + u];

    // x-prefetch: lanes 0..7 of each wave cover the 40 (b_loc, i) slots
    const int lane = tid & 63, wv = tid >> 6;
    const int slot = wv * 8 + lane;          // meaningful only when lane<8
    const bool pf = (lane < 8);
    const int pb = slot / kI, pi = slot - pb * kI;
    const size_t xstride = (size_t)kB * kI;

    // ---- initial staging (t=0) ----
    if (pf) x_s[0][pb][pi] = x[(size_t)b0 * kI + slot];
    if (tid < BPB * kH) h_s[0][tid / kH][tid % kH] = hx[(size_t)b0 * kH + tid];
    __syncthreads();

    const float* xpf_p = x + xstride + (size_t)b0 * kI + slot;   // x[t=1]
    float* outp = out + (size_t)b * kH + u;

    for (int t = 0; t < kT; ++t) {
        const int rb = t & 1, wb = rb ^ 1;

        // prefetch x[t+1]; HBM latency hides under the FMAs
        float xp = 0.0f;
        if ((t + 1 < kT) && pf) xp = *xpf_p;

        // vector LDS reads (same-address broadcast within each b_loc group)
        const float4* xs4 = reinterpret_cast<const float4*>(&x_s[rb][b_loc][0]);
        const float4 xa = xs4[0], xb2 = xs4[1];
        const float2 xc = *reinterpret_cast<const float2*>(&x_s[rb][b_loc][8]);
        const float4* hs4 = reinterpret_cast<const float4*>(&h_s[rb][b_loc][0]);
        const float4 h0 = hs4[0], h1 = hs4[1], h2 = hs4[2], h3 = hs4[3], h4 = hs4[4];

        // 30 FMAs in two chains
        float a = bias, a2 = 0.0f;
        a  = fmaf(Wih[0], xa.x,  a );  a2 = fmaf(Wih[1], xa.y,  a2);
        a  = fmaf(Wih[2], xa.z,  a );  a2 = fmaf(Wih[3], xa.w,  a2);
        a  = fmaf(Wih[4], xb2.x, a );  a2 = fmaf(Wih[5], xb2.y, a2);
        a  = fmaf(Wih[6], xb2.z, a );  a2 = fmaf(Wih[7], xb2.w, a2);
        a  = fmaf(Wih[8], xc.x,  a );  a2 = fmaf(Wih[9], xc.y,  a2);
        a  = fmaf(Whh[0],  h0.x, a );  a2 = fmaf(Whh[1],  h0.y, a2);
        a  = fmaf(Whh[2],  h0.z, a );  a2 = fmaf(Whh[3],  h0.w, a2);
        a  = fmaf(Whh[4],  h1.x, a );  a2 = fmaf(Whh[5],  h1.y, a2);
        a  = fmaf(Whh[6],  h1.z, a );  a2 = fmaf(Whh[7],  h1.w, a2);
        a  = fmaf(Whh[8],  h2.x, a );  a2 = fmaf(Whh[9],  h2.y, a2);
        a  = fmaf(Whh[10], h2.z, a );  a2 = fmaf(Whh[11], h2.w, a2);
        a  = fmaf(Whh[12], h3.x, a );  a2 = fmaf(Whh[13], h3.y, a2);
        a  = fmaf(Whh[14], h3.z, a );  a2 = fmaf(Whh[15], h3.w, a2);
        a  = fmaf(Whh[16], h4.x, a );  a2 = fmaf(Whh[17], h4.y, a2);
        a  = fmaf(Whh[18], h4.z, a );  a2 = fmaf(Whh[19], h4.w, a2);
        a += a2;

        float e = __builtin_amdgcn_exp2f(c0 * a);
        float act = fmaf(__builtin_amdgcn_rcpf(1.0f + e), c1, c2);

        // broadcast gates i,f,g within each 4-lane group: DPP quad_perm (VALU)
        const int ai = __float_as_int(act);
        const float iv = __int_as_float(__builtin_amdgcn_update_dpp(0, ai, 0x00, 0xF, 0xF, true));
        const float fv = __int_as_float(__builtin_amdgcn_update_dpp(0, ai, 0x55, 0xF, 0xF, true));
        const float gv = __int_as_float(__builtin_amdgcn_update_dpp(0, ai, 0xAA, 0xF, 0xF, true));

        c = fmaf(fv, c, iv * gv);                    // redundant in all 4 lanes
        float e2 = __builtin_amdgcn_exp2f(-2.885390082f * c);
        float th = fmaf(__builtin_amdgcn_rcpf(1.0f + e2), 2.0f, -1.0f);
        float hn = act * th;                         // valid on k==3 (act==o)

        if (k == 3) {
            h_s[wb][b_loc][u] = hn;
            *outp = hn;
        }
        if (pf) x_s[wb][pb][pi] = xp;

        outp  += (size_t)kB * kH;
        xpf_p += xstride;
        __syncthreads();                             // writes -> next step's reads
    }
}

extern "C" void kernel_launch(void* const* d_in, const int* in_sizes, int n_in,
                              void* d_out, int out_size, void* d_ws, size_t ws_size,
                              hipStream_t stream) {
    const float* x    = (const float*)d_in[0];
    const float* hx   = (const float*)d_in[1];
    const float* cx   = (const float*)d_in[2];
    const float* W_ih = (const float*)d_in[3];
    const float* W_hh = (const float*)d_in[4];
    const float* b_ih = (const float*)d_in[5];
    const float* b_hh = (const float*)d_in[6];
    float* out = (float*)d_out;

    lstm_v5<<<kB / BPB, THREADS, 0, stream>>>(x, hx, cx, W_ih, W_hh, b_ih, b_hh, out);
}